// Round 1
// baseline (10149.378 us; speedup 1.0000x reference)
//
#include <hip/hip_runtime.h>
#include <math.h>

#define NN 100000
#define NE 1000000
#define D  64

// ---------------- edge kernels (segment sums via hw f32 atomics) ----------------
// thread = (edge, 4-channel chunk): E*16 threads, coalesced 256B row reads.

__global__ __launch_bounds__(256) void edge_pass1(
    const float* __restrict__ nfeats, const float* __restrict__ efeats,
    const int* __restrict__ src, const int* __restrict__ dst,
    float* __restrict__ hsum, float* __restrict__ efsum, float* __restrict__ cnt)
{
    int idx = blockIdx.x * 256 + threadIdx.x;
    int e = idx >> 4, c = (idx & 15) << 2;
    if (e >= NE) return;
    int s = src[e], d = dst[e];
    float4 ef = *(const float4*)(efeats + (size_t)e * D + c);
    float4 nf = *(const float4*)(nfeats + (size_t)s * D + c);
    float* ep = efsum + (size_t)d * D + c;
    float* hp = hsum  + (size_t)d * D + c;
    unsafeAtomicAdd(ep + 0, ef.x); unsafeAtomicAdd(ep + 1, ef.y);
    unsafeAtomicAdd(ep + 2, ef.z); unsafeAtomicAdd(ep + 3, ef.w);
    unsafeAtomicAdd(hp + 0, nf.x); unsafeAtomicAdd(hp + 1, nf.y);
    unsafeAtomicAdd(hp + 2, nf.z); unsafeAtomicAdd(hp + 3, nf.w);
    if (c == 0) unsafeAtomicAdd(cnt + d, 1.0f);
}

__global__ __launch_bounds__(256) void edge_pass_ef(
    const float* __restrict__ efeats, const int* __restrict__ dst,
    const int* __restrict__ perm, float* __restrict__ efsum)
{
    int idx = blockIdx.x * 256 + threadIdx.x;
    int e = idx >> 4, c = (idx & 15) << 2;
    if (e >= NE) return;
    int d = dst[e], p = perm[e];
    float4 ef = *(const float4*)(efeats + (size_t)p * D + c);
    float* ep = efsum + (size_t)d * D + c;
    unsafeAtomicAdd(ep + 0, ef.x); unsafeAtomicAdd(ep + 1, ef.y);
    unsafeAtomicAdd(ep + 2, ef.z); unsafeAtomicAdd(ep + 3, ef.w);
}

__global__ __launch_bounds__(256) void edge_pass_h(
    const float* __restrict__ h, const int* __restrict__ src,
    const int* __restrict__ dst, float* __restrict__ hsum)
{
    int idx = blockIdx.x * 256 + threadIdx.x;
    int e = idx >> 4, c = (idx & 15) << 2;
    if (e >= NE) return;
    int s = src[e], d = dst[e];
    float4 hv = *(const float4*)(h + (size_t)s * D + c);
    float* hp = hsum + (size_t)d * D + c;
    unsafeAtomicAdd(hp + 0, hv.x); unsafeAtomicAdd(hp + 1, hv.y);
    unsafeAtomicAdd(hp + 2, hv.z); unsafeAtomicAdd(hp + 3, hv.w);
}

// ---------------- node GEMM: out[n,o] = f( sum_k [A0[n]|A1[n]][k] * W[o][k] ) ----------------
// 64 nodes x 64 outs per block, 256 threads, 4x4 per thread.
// mode 0: msg  -> val=(acc + cnt*b)/max(cnt,1), store
// mode 1: apply-> val=relu(acc+b), store
// mode 2: apply+loss -> relu, softplus-accumulate into loss_out, no store
__global__ __launch_bounds__(256) void node_gemm(
    const float* __restrict__ A0, const float* __restrict__ A1,
    const float* __restrict__ W, const float* __restrict__ bias,
    const float* __restrict__ cnt, float* __restrict__ out,
    int mode, int is_neg, float* __restrict__ loss_out)
{
    __shared__ __align__(16) float As[D][68];    // [node][k-half] 17.4 KB
    __shared__ __align__(16) float Bs[128][68];  // [k][o]         34.8 KB
    int tid = threadIdx.x;
    int block0 = blockIdx.x * 64;
    int tx4 = (tid & 15) << 2;      // out col base
    int ty4 = (tid >> 4) << 2;      // node row base

    // stage W transposed: Bs[k][o] = W[o*128+k]
#pragma unroll
    for (int i = 0; i < 32; ++i) {
        int idx = i * 256 + tid;
        int o = idx >> 7, k = idx & 127;
        Bs[k][o] = W[idx];
    }

    float acc[4][4] = {};
#pragma unroll
    for (int half = 0; half < 2; ++half) {
        const float* Asrc = half ? A1 : A0;
        __syncthreads();   // also guards Bs before first use
        // stage 64x64 A-half
#pragma unroll
        for (int g = 0; g < 4; ++g) {
            int idx = g * 256 + tid;
            int node = idx >> 4, c = (idx & 15) << 2;
            int gn = block0 + node;
            float4 v = make_float4(0.f, 0.f, 0.f, 0.f);
            if (gn < NN) v = *(const float4*)(Asrc + (size_t)gn * D + c);
            *(float4*)&As[node][c] = v;
        }
        __syncthreads();
        int hb = half * 64;
        for (int k0 = 0; k0 < 64; k0 += 4) {
            float a[4][4];
#pragma unroll
            for (int i = 0; i < 4; ++i)
                *(float4*)&a[i][0] = *(const float4*)&As[ty4 + i][k0];
#pragma unroll
            for (int kk = 0; kk < 4; ++kk) {
                float4 b = *(const float4*)&Bs[hb + k0 + kk][tx4];
#pragma unroll
                for (int i = 0; i < 4; ++i) {
                    acc[i][0] += a[i][kk] * b.x;
                    acc[i][1] += a[i][kk] * b.y;
                    acc[i][2] += a[i][kk] * b.z;
                    acc[i][3] += a[i][kk] * b.w;
                }
            }
        }
    }

    float lsum = 0.f;
#pragma unroll
    for (int i = 0; i < 4; ++i) {
        int gn = block0 + ty4 + i;
        if (gn >= NN) continue;
        if (mode == 0) {
            float c = cnt[gn];
            float inv = 1.0f / fmaxf(c, 1.0f);
#pragma unroll
            for (int j = 0; j < 4; ++j) {
                int o = tx4 + j;
                out[(size_t)gn * D + o] = (acc[i][j] + c * bias[o]) * inv;
            }
        } else if (mode == 1) {
#pragma unroll
            for (int j = 0; j < 4; ++j) {
                int o = tx4 + j;
                out[(size_t)gn * D + o] = fmaxf(acc[i][j] + bias[o], 0.f);
            }
        } else {
#pragma unroll
            for (int j = 0; j < 4; ++j) {
                int o = tx4 + j;
                float x = fmaxf(acc[i][j] + bias[o], 0.f);
                float l = log1pf(expf(-x));   // pos: softplus(-x); neg adds x
                if (is_neg) l += x;
                lsum += l;
            }
        }
    }
    if (mode == 2) {
#pragma unroll
        for (int off = 32; off; off >>= 1) lsum += __shfl_down(lsum, off, 64);
        if ((tid & 63) == 0)
            unsafeAtomicAdd(loss_out, lsum * (1.0f / 6400000.0f)); // / (N*64)
    }
}

// ---------------- launch ----------------
extern "C" void kernel_launch(void* const* d_in, const int* in_sizes, int n_in,
                              void* d_out, int out_size, void* d_ws, size_t ws_size,
                              hipStream_t stream) {
    (void)in_sizes; (void)n_in; (void)out_size; (void)ws_size;
    const float* nfeats = (const float*)d_in[0];
    const float* efeats = (const float*)d_in[1];
    const int*   src    = (const int*)d_in[2];
    const int*   dst    = (const int*)d_in[3];
    const int*   perm   = (const int*)d_in[4];
    const float* Wmsg0  = (const float*)d_in[5];
    const float* bmsg0  = (const float*)d_in[6];
    const float* Wap0   = (const float*)d_in[7];
    const float* bap0   = (const float*)d_in[8];
    const float* Wmsg1  = (const float*)d_in[9];
    const float* bmsg1  = (const float*)d_in[10];
    const float* Wap1   = (const float*)d_in[11];
    const float* bap1   = (const float*)d_in[12];
    float* out = (float*)d_out;

    const size_t NV = (size_t)NN * D;   // 6.4M floats
    float* ws     = (float*)d_ws;
    float* cnt    = ws;                 // NN
    float* efs    = cnt + NN;           // NV (efsum, reused pos->neg)
    float* hsum0  = efs + NV;           // NV (shared by both encodes)
    float* h1     = hsum0 + NV;         // NV
    float* hsum1  = h1 + NV;            // NV
    float* hneigh = hsum1 + NV;         // NV   total ~128.4 MB

    const int EG = (NE * 16) / 256;          // 62500 edge blocks
    const int NG = (NN + 63) / 64;           // 1563 node blocks

    // zero cnt+efsum+hsum0 (contiguous) and the output scalar
    hipMemsetAsync(cnt, 0, (NN + 2 * NV) * sizeof(float), stream);
    hipMemsetAsync(d_out, 0, sizeof(float), stream);

    // shared: cnt, hsum0 (= sum nfeats[src]), efsum_pos
    edge_pass1<<<EG, 256, 0, stream>>>(nfeats, efeats, src, dst, hsum0, efs, cnt);

    // ---- positive encode ----
    node_gemm<<<NG, 256, 0, stream>>>(hsum0, efs, Wmsg0, bmsg0, cnt, hneigh, 0, 0, nullptr);
    node_gemm<<<NG, 256, 0, stream>>>(nfeats, hneigh, Wap0, bap0, nullptr, h1, 1, 0, nullptr);
    hipMemsetAsync(hsum1, 0, NV * sizeof(float), stream);
    edge_pass_h<<<EG, 256, 0, stream>>>(h1, src, dst, hsum1);
    node_gemm<<<NG, 256, 0, stream>>>(hsum1, efs, Wmsg1, bmsg1, cnt, hneigh, 0, 0, nullptr);
    node_gemm<<<NG, 256, 0, stream>>>(h1, hneigh, Wap1, bap1, nullptr, nullptr, 2, 0, out);

    // ---- negative encode (efsum from permuted edge features; hsum0/cnt reused) ----
    hipMemsetAsync(efs, 0, NV * sizeof(float), stream);
    edge_pass_ef<<<EG, 256, 0, stream>>>(efeats, dst, perm, efs);
    node_gemm<<<NG, 256, 0, stream>>>(hsum0, efs, Wmsg0, bmsg0, cnt, hneigh, 0, 0, nullptr);
    node_gemm<<<NG, 256, 0, stream>>>(nfeats, hneigh, Wap0, bap0, nullptr, h1, 1, 0, nullptr);
    hipMemsetAsync(hsum1, 0, NV * sizeof(float), stream);
    edge_pass_h<<<EG, 256, 0, stream>>>(h1, src, dst, hsum1);
    node_gemm<<<NG, 256, 0, stream>>>(hsum1, efs, Wmsg1, bmsg1, cnt, hneigh, 0, 0, nullptr);
    node_gemm<<<NG, 256, 0, stream>>>(h1, hneigh, Wap1, bap1, nullptr, nullptr, 2, 1, out);
}

// Round 2
// 3813.807 us; speedup vs baseline: 2.6612x; 2.6612x over previous
//
#include <hip/hip_runtime.h>
#include <math.h>

#define NN 100000
#define NE 1000000
#define D  64
#define NB_SCAN 391   // ceil(NN/256)

// ================= CSR build (counting sort by dst) =================

__global__ __launch_bounds__(256) void k_hist(
    const int* __restrict__ dst, int* __restrict__ counts, int* __restrict__ rank)
{
    int e = blockIdx.x * 256 + threadIdx.x;
    if (e >= NE) return;
    rank[e] = atomicAdd(&counts[dst[e]], 1);
}

__global__ __launch_bounds__(256) void k_scan1(
    const int* __restrict__ counts, int* __restrict__ row_start, int* __restrict__ bsum)
{
    __shared__ int s[256];
    int t = threadIdx.x;
    int i = blockIdx.x * 256 + t;
    int v = (i < NN) ? counts[i] : 0;
    s[t] = v; __syncthreads();
#pragma unroll
    for (int off = 1; off < 256; off <<= 1) {
        int add = (t >= off) ? s[t - off] : 0;
        __syncthreads();
        s[t] += add;
        __syncthreads();
    }
    if (i < NN) row_start[i] = s[t] - v;       // local exclusive
    if (t == 255) bsum[blockIdx.x] = s[255];   // block total
}

__global__ __launch_bounds__(512) void k_scan2(
    const int* __restrict__ bsum, int* __restrict__ boff, int* __restrict__ row_start)
{
    __shared__ int s[512];
    int t = threadIdx.x;
    int v = (t < NB_SCAN) ? bsum[t] : 0;
    s[t] = v; __syncthreads();
#pragma unroll
    for (int off = 1; off < 512; off <<= 1) {
        int add = (t >= off) ? s[t - off] : 0;
        __syncthreads();
        s[t] += add;
        __syncthreads();
    }
    if (t < NB_SCAN) boff[t] = s[t] - v;       // exclusive block offsets
    if (t == 0) row_start[NN] = NE;
}

__global__ __launch_bounds__(256) void k_scan3(
    int* __restrict__ row_start, const int* __restrict__ boff)
{
    int i = blockIdx.x * 256 + threadIdx.x;
    if (i < NN) row_start[i] += boff[i >> 8];
}

__global__ __launch_bounds__(256) void k_scatter(
    const int* __restrict__ dst, const int* __restrict__ src,
    const int* __restrict__ perm, const int* __restrict__ rank,
    const int* __restrict__ row_start, int4* __restrict__ sorted)
{
    int e = blockIdx.x * 256 + threadIdx.x;
    if (e >= NE) return;
    int pos = row_start[dst[e]] + rank[e];
    sorted[pos] = make_int4(src[e], e, perm[e], 0);
}

// ================= pull-based segment sums (no atomics) =================
// one wave per node; lane = channel.

__global__ __launch_bounds__(256) void pull_pass1(
    const int4* __restrict__ sorted, const int* __restrict__ row_start,
    const float* __restrict__ nfeats, const float* __restrict__ efeats,
    float* __restrict__ hsum0, float* __restrict__ efs)
{
    int gt = blockIdx.x * 256 + threadIdx.x;
    int w = gt >> 6, lane = gt & 63;
    if (w >= NN) return;
    int beg = row_start[w], end = row_start[w + 1];
    float ah = 0.f, ae = 0.f;
    for (int i = beg; i < end; ++i) {
        int4 q = sorted[i];          // broadcast load (same addr all lanes)
        ae += efeats[(size_t)q.y * D + lane];
        ah += nfeats[(size_t)q.x * D + lane];
    }
    hsum0[(size_t)w * D + lane] = ah;
    efs[(size_t)w * D + lane] = ae;
}

__global__ __launch_bounds__(256) void pull_h(
    const int4* __restrict__ sorted, const int* __restrict__ row_start,
    const float* __restrict__ h, float* __restrict__ hsum)
{
    int gt = blockIdx.x * 256 + threadIdx.x;
    int w = gt >> 6, lane = gt & 63;
    if (w >= NN) return;
    int beg = row_start[w], end = row_start[w + 1];
    float a = 0.f;
    for (int i = beg; i < end; ++i) {
        int4 q = sorted[i];
        a += h[(size_t)q.x * D + lane];
    }
    hsum[(size_t)w * D + lane] = a;
}

__global__ __launch_bounds__(256) void pull_ef(
    const int4* __restrict__ sorted, const int* __restrict__ row_start,
    const float* __restrict__ efeats, float* __restrict__ efs)
{
    int gt = blockIdx.x * 256 + threadIdx.x;
    int w = gt >> 6, lane = gt & 63;
    if (w >= NN) return;
    int beg = row_start[w], end = row_start[w + 1];
    float a = 0.f;
    for (int i = beg; i < end; ++i) {
        int4 q = sorted[i];
        a += efeats[(size_t)q.z * D + lane];
    }
    efs[(size_t)w * D + lane] = a;
}

// ================= fused SAGE layer: msg GEMM + apply GEMM =================
// 64 nodes x 64 outs per block, 256 threads, 4x4/thread (rows ty+16*i).
// msg  = (Hsum|Esum) @ Wmsg^T, scaled (acc + cnt*b)/max(cnt,1)
// hout = relu((Hprev|msg) @ Wap^T + bap); do_loss: softplus-reduce instead of store.
__global__ __launch_bounds__(256) void fused_layer(
    const float* __restrict__ Hsum, const float* __restrict__ Esum,
    const float* __restrict__ Hprev, const int* __restrict__ counts,
    const float* __restrict__ Wmsg, const float* __restrict__ bmsg,
    const float* __restrict__ Wap, const float* __restrict__ bap,
    float* __restrict__ Hout, int do_loss, int is_neg, float* __restrict__ loss_out)
{
    __shared__ __align__(16) float As[64][68];
    __shared__ __align__(16) float Bs[128][68];
    int tid = threadIdx.x;
    int block0 = blockIdx.x * 64;
    int tx = tid & 15, ty = tid >> 4;
    int tx4 = tx << 2;

    // ---- stage Wmsg^T: Bs[k][o] = Wmsg[o*128+k] (coalesced global reads) ----
#pragma unroll 8
    for (int i = 0; i < 32; ++i) {
        int idx = i * 256 + tid;
        Bs[idx & 127][idx >> 7] = Wmsg[idx];
    }

    float acc[4][4] = {};
#pragma unroll
    for (int half = 0; half < 2; ++half) {
        const float* Asrc = half ? Esum : Hsum;
        __syncthreads();            // guards Bs on first pass, As reuse after
#pragma unroll
        for (int g = 0; g < 4; ++g) {
            int idx = g * 256 + tid;
            int node = idx >> 4, c = (idx & 15) << 2;
            int gn = block0 + node;
            float4 v = make_float4(0.f, 0.f, 0.f, 0.f);
            if (gn < NN) v = *(const float4*)(Asrc + (size_t)gn * D + c);
            *(float4*)&As[node][c] = v;
        }
        __syncthreads();
        int hb = half * 64;
        for (int k0 = 0; k0 < 64; k0 += 4) {
            float a[4][4];
#pragma unroll
            for (int i = 0; i < 4; ++i)
                *(float4*)&a[i][0] = *(const float4*)&As[ty + 16 * i][k0];
#pragma unroll
            for (int kk = 0; kk < 4; ++kk) {
                float4 b = *(const float4*)&Bs[hb + k0 + kk][tx4];
#pragma unroll
                for (int i = 0; i < 4; ++i) {
                    acc[i][0] += a[i][kk] * b.x;
                    acc[i][1] += a[i][kk] * b.y;
                    acc[i][2] += a[i][kk] * b.z;
                    acc[i][3] += a[i][kk] * b.w;
                }
            }
        }
    }

    // ---- msg epilogue: (acc + cnt*bmsg)/max(cnt,1) ----
    float bm[4];
#pragma unroll
    for (int j = 0; j < 4; ++j) bm[j] = bmsg[tx4 + j];
    float msg[4][4];
#pragma unroll
    for (int i = 0; i < 4; ++i) {
        int gn = block0 + ty + 16 * i;
        float c = (gn < NN) ? (float)counts[gn] : 0.f;
        float inv = 1.0f / fmaxf(c, 1.0f);
#pragma unroll
        for (int j = 0; j < 4; ++j) msg[i][j] = (acc[i][j] + c * bm[j]) * inv;
    }

    // ---- phase 2: apply GEMM ----
    __syncthreads();    // all reads of As(Esum)/Bs(Wmsg) complete
#pragma unroll 8
    for (int i = 0; i < 32; ++i) {
        int idx = i * 256 + tid;
        Bs[idx & 127][idx >> 7] = Wap[idx];
    }
#pragma unroll
    for (int i = 0; i < 4; ++i)
        *(float4*)&As[ty + 16 * i][tx4] = make_float4(msg[i][0], msg[i][1], msg[i][2], msg[i][3]);
    __syncthreads();

    float acc2[4][4] = {};
    // msg half (k in [64,128))
    for (int k0 = 0; k0 < 64; k0 += 4) {
        float a[4][4];
#pragma unroll
        for (int i = 0; i < 4; ++i)
            *(float4*)&a[i][0] = *(const float4*)&As[ty + 16 * i][k0];
#pragma unroll
        for (int kk = 0; kk < 4; ++kk) {
            float4 b = *(const float4*)&Bs[64 + k0 + kk][tx4];
#pragma unroll
            for (int i = 0; i < 4; ++i) {
                acc2[i][0] += a[i][kk] * b.x;
                acc2[i][1] += a[i][kk] * b.y;
                acc2[i][2] += a[i][kk] * b.z;
                acc2[i][3] += a[i][kk] * b.w;
            }
        }
    }
    __syncthreads();
    // Hprev half (k in [0,64))
#pragma unroll
    for (int g = 0; g < 4; ++g) {
        int idx = g * 256 + tid;
        int node = idx >> 4, c = (idx & 15) << 2;
        int gn = block0 + node;
        float4 v = make_float4(0.f, 0.f, 0.f, 0.f);
        if (gn < NN) v = *(const float4*)(Hprev + (size_t)gn * D + c);
        *(float4*)&As[node][c] = v;
    }
    __syncthreads();
    for (int k0 = 0; k0 < 64; k0 += 4) {
        float a[4][4];
#pragma unroll
        for (int i = 0; i < 4; ++i)
            *(float4*)&a[i][0] = *(const float4*)&As[ty + 16 * i][k0];
#pragma unroll
        for (int kk = 0; kk < 4; ++kk) {
            float4 b = *(const float4*)&Bs[k0 + kk][tx4];
#pragma unroll
            for (int i = 0; i < 4; ++i) {
                acc2[i][0] += a[i][kk] * b.x;
                acc2[i][1] += a[i][kk] * b.y;
                acc2[i][2] += a[i][kk] * b.z;
                acc2[i][3] += a[i][kk] * b.w;
            }
        }
    }

    // ---- epilogue ----
    float ba[4];
#pragma unroll
    for (int j = 0; j < 4; ++j) ba[j] = bap[tx4 + j];
    if (!do_loss) {
#pragma unroll
        for (int i = 0; i < 4; ++i) {
            int gn = block0 + ty + 16 * i;
            if (gn >= NN) continue;
#pragma unroll
            for (int j = 0; j < 4; ++j)
                Hout[(size_t)gn * D + tx4 + j] = fmaxf(acc2[i][j] + ba[j], 0.f);
        }
    } else {
        float lsum = 0.f;
#pragma unroll
        for (int i = 0; i < 4; ++i) {
            int gn = block0 + ty + 16 * i;
            if (gn >= NN) continue;
#pragma unroll
            for (int j = 0; j < 4; ++j) {
                float x = fmaxf(acc2[i][j] + ba[j], 0.f);
                float l = log1pf(expf(-x));   // pos: softplus(-x); neg adds x
                if (is_neg) l += x;
                lsum += l;
            }
        }
#pragma unroll
        for (int off = 32; off; off >>= 1) lsum += __shfl_down(lsum, off, 64);
        if ((tid & 63) == 0)
            unsafeAtomicAdd(loss_out, lsum * (1.0f / 6400000.0f)); // / (N*64)
    }
}

// ================= launch =================
extern "C" void kernel_launch(void* const* d_in, const int* in_sizes, int n_in,
                              void* d_out, int out_size, void* d_ws, size_t ws_size,
                              hipStream_t stream) {
    (void)in_sizes; (void)n_in; (void)out_size; (void)ws_size;
    const float* nfeats = (const float*)d_in[0];
    const float* efeats = (const float*)d_in[1];
    const int*   src    = (const int*)d_in[2];
    const int*   dst    = (const int*)d_in[3];
    const int*   perm   = (const int*)d_in[4];
    const float* Wmsg0  = (const float*)d_in[5];
    const float* bmsg0  = (const float*)d_in[6];
    const float* Wap0   = (const float*)d_in[7];
    const float* bap0   = (const float*)d_in[8];
    const float* Wmsg1  = (const float*)d_in[9];
    const float* bmsg1  = (const float*)d_in[10];
    const float* Wap1   = (const float*)d_in[11];
    const float* bap1   = (const float*)d_in[12];
    float* out = (float*)d_out;

    // ---- workspace layout (16B-aligned chunks) ----
    const size_t NV = (size_t)NN * D;
    char* p = (char*)d_ws;
    int4* sorted   = (int4*)p;               p += (size_t)NE * 16;   // 16 MB
    int*  rank     = (int*)p;                p += (size_t)NE * 4;    // 4 MB
    int*  counts   = (int*)p;                p += ((NN + 15) & ~15) * 4;
    int*  rowst    = (int*)p;                p += ((NN + 16) & ~15) * 4;
    int*  bsum     = (int*)p;                p += 512 * 4;
    int*  boff     = (int*)p;                p += 512 * 4;
    float* efs     = (float*)p;              p += NV * 4;            // 25.6 MB
    float* hsum0   = (float*)p;              p += NV * 4;
    float* h1      = (float*)p;              p += NV * 4;
    float* hsum1   = (float*)p;              p += NV * 4;

    const int EGb = (NE + 255) / 256;        // 3907
    const int PGb = ((size_t)NN * 64 + 255) / 256;  // 25000
    const int NG  = (NN + 63) / 64;          // 1563

    hipMemsetAsync(counts, 0, (size_t)NN * 4, stream);
    hipMemsetAsync(d_out, 0, 4, stream);

    // ---- CSR build ----
    k_hist<<<EGb, 256, 0, stream>>>(dst, counts, rank);
    k_scan1<<<NB_SCAN, 256, 0, stream>>>(counts, rowst, bsum);
    k_scan2<<<1, 512, 0, stream>>>(bsum, boff, rowst);
    k_scan3<<<NB_SCAN, 256, 0, stream>>>(rowst, boff);
    k_scatter<<<EGb, 256, 0, stream>>>(dst, src, perm, rank, rowst, sorted);

    // ---- positive encode ----
    pull_pass1<<<PGb, 256, 0, stream>>>(sorted, rowst, nfeats, efeats, hsum0, efs);
    fused_layer<<<NG, 256, 0, stream>>>(hsum0, efs, nfeats, counts,
                                        Wmsg0, bmsg0, Wap0, bap0, h1, 0, 0, nullptr);
    pull_h<<<PGb, 256, 0, stream>>>(sorted, rowst, h1, hsum1);
    fused_layer<<<NG, 256, 0, stream>>>(hsum1, efs, h1, counts,
                                        Wmsg1, bmsg1, Wap1, bap1, nullptr, 1, 0, out);

    // ---- negative encode (efsum from permuted edge features) ----
    pull_ef<<<PGb, 256, 0, stream>>>(sorted, rowst, efeats, efs);
    fused_layer<<<NG, 256, 0, stream>>>(hsum0, efs, nfeats, counts,
                                        Wmsg0, bmsg0, Wap0, bap0, h1, 0, 0, nullptr);
    pull_h<<<PGb, 256, 0, stream>>>(sorted, rowst, h1, hsum1);
    fused_layer<<<NG, 256, 0, stream>>>(hsum1, efs, h1, counts,
                                        Wmsg1, bmsg1, Wap1, bap1, nullptr, 1, 1, out);
}

// Round 3
// 1335.655 us; speedup vs baseline: 7.5988x; 2.8554x over previous
//
#include <hip/hip_runtime.h>
#include <math.h>

#define NN 100000
#define NE 1000000
#define D  64
#define NB_SCAN 391   // ceil(NN/256)

// ================= CSR build (counting sort by dst) =================

__global__ __launch_bounds__(256) void k_hist(
    const int* __restrict__ dst, int* __restrict__ counts, int* __restrict__ rank)
{
    int e = blockIdx.x * 256 + threadIdx.x;
    if (e >= NE) return;
    rank[e] = atomicAdd(&counts[dst[e]], 1);
}

__global__ __launch_bounds__(256) void k_scan1(
    const int* __restrict__ counts, int* __restrict__ row_start, int* __restrict__ bsum)
{
    __shared__ int s[256];
    int t = threadIdx.x;
    int i = blockIdx.x * 256 + t;
    int v = (i < NN) ? counts[i] : 0;
    s[t] = v; __syncthreads();
#pragma unroll
    for (int off = 1; off < 256; off <<= 1) {
        int add = (t >= off) ? s[t - off] : 0;
        __syncthreads();
        s[t] += add;
        __syncthreads();
    }
    if (i < NN) row_start[i] = s[t] - v;       // local exclusive
    if (t == 255) bsum[blockIdx.x] = s[255];   // block total
}

__global__ __launch_bounds__(512) void k_scan2(
    const int* __restrict__ bsum, int* __restrict__ boff, int* __restrict__ row_start)
{
    __shared__ int s[512];
    int t = threadIdx.x;
    int v = (t < NB_SCAN) ? bsum[t] : 0;
    s[t] = v; __syncthreads();
#pragma unroll
    for (int off = 1; off < 512; off <<= 1) {
        int add = (t >= off) ? s[t - off] : 0;
        __syncthreads();
        s[t] += add;
        __syncthreads();
    }
    if (t < NB_SCAN) boff[t] = s[t] - v;       // exclusive block offsets
    if (t == 0) row_start[NN] = NE;
}

__global__ __launch_bounds__(256) void k_scan3(
    int* __restrict__ row_start, const int* __restrict__ boff)
{
    int i = blockIdx.x * 256 + threadIdx.x;
    if (i < NN) row_start[i] += boff[i >> 8];
}

__global__ __launch_bounds__(256) void k_scatter(
    const int* __restrict__ dst, const int* __restrict__ src,
    const int* __restrict__ perm, const int* __restrict__ rank,
    const int* __restrict__ row_start, int4* __restrict__ sorted)
{
    int e = blockIdx.x * 256 + threadIdx.x;
    if (e >= NE) return;
    int pos = row_start[dst[e]] + rank[e];
    sorted[pos] = make_int4(src[e], e, perm[e], 0);
}

// ================= pull-based segment sums (no atomics) =================
// one wave per node; lane = channel.

__global__ __launch_bounds__(256) void pull_pass1(
    const int4* __restrict__ sorted, const int* __restrict__ row_start,
    const float* __restrict__ nfeats, const float* __restrict__ efeats,
    float* __restrict__ hsum0, float* __restrict__ efs)
{
    int gt = blockIdx.x * 256 + threadIdx.x;
    int w = gt >> 6, lane = gt & 63;
    if (w >= NN) return;
    int beg = row_start[w], end = row_start[w + 1];
    float ah = 0.f, ae = 0.f;
    for (int i = beg; i < end; ++i) {
        int4 q = sorted[i];          // broadcast load (same addr all lanes)
        ae += efeats[(size_t)q.y * D + lane];
        ah += nfeats[(size_t)q.x * D + lane];
    }
    hsum0[(size_t)w * D + lane] = ah;
    efs[(size_t)w * D + lane] = ae;
}

__global__ __launch_bounds__(256) void pull_h(
    const int4* __restrict__ sorted, const int* __restrict__ row_start,
    const float* __restrict__ h, float* __restrict__ hsum)
{
    int gt = blockIdx.x * 256 + threadIdx.x;
    int w = gt >> 6, lane = gt & 63;
    if (w >= NN) return;
    int beg = row_start[w], end = row_start[w + 1];
    float a = 0.f;
    for (int i = beg; i < end; ++i) {
        int4 q = sorted[i];
        a += h[(size_t)q.x * D + lane];
    }
    hsum[(size_t)w * D + lane] = a;
}

__global__ __launch_bounds__(256) void pull_ef(
    const int4* __restrict__ sorted, const int* __restrict__ row_start,
    const float* __restrict__ efeats, float* __restrict__ efs)
{
    int gt = blockIdx.x * 256 + threadIdx.x;
    int w = gt >> 6, lane = gt & 63;
    if (w >= NN) return;
    int beg = row_start[w], end = row_start[w + 1];
    float a = 0.f;
    for (int i = beg; i < end; ++i) {
        int4 q = sorted[i];
        a += efeats[(size_t)q.z * D + lane];
    }
    efs[(size_t)w * D + lane] = a;
}

// ================= fused SAGE layer: msg GEMM + apply GEMM =================
// 64 nodes x 64 outs per block, 256 threads, 4x4/thread (rows ty+16*i).
// __launch_bounds__(256,4) caps VGPR at 128; #pragma unroll 1 on k-loops
// prevents the full-unroll register balloon that caused scratch spills (R2:
// VGPR=256, 2.3 GB HBM traffic/dispatch from spill round-trips).
__global__ __launch_bounds__(256, 4) void fused_layer(
    const float* __restrict__ Hsum, const float* __restrict__ Esum,
    const float* __restrict__ Hprev, const int* __restrict__ counts,
    const float* __restrict__ Wmsg, const float* __restrict__ bmsg,
    const float* __restrict__ Wap, const float* __restrict__ bap,
    float* __restrict__ Hout, int do_loss, int is_neg, float* __restrict__ loss_out)
{
    __shared__ __align__(16) float As[64][68];
    __shared__ __align__(16) float Bs[128][68];
    int tid = threadIdx.x;
    int block0 = blockIdx.x * 64;
    int tx = tid & 15, ty = tid >> 4;
    int tx4 = tx << 2;

    // ---- stage Wmsg^T: Bs[k][o] = Wmsg[o*128+k] (coalesced global reads) ----
#pragma unroll 1
    for (int i = 0; i < 32; ++i) {
        int idx = i * 256 + tid;
        Bs[idx & 127][idx >> 7] = Wmsg[idx];
    }

    float acc[4][4] = {};
#pragma unroll
    for (int half = 0; half < 2; ++half) {
        const float* Asrc = half ? Esum : Hsum;
        __syncthreads();            // guards Bs on first pass, As reuse after
#pragma unroll
        for (int g = 0; g < 4; ++g) {
            int idx = g * 256 + tid;
            int node = idx >> 4, c = (idx & 15) << 2;
            int gn = block0 + node;
            float4 v = make_float4(0.f, 0.f, 0.f, 0.f);
            if (gn < NN) v = *(const float4*)(Asrc + (size_t)gn * D + c);
            *(float4*)&As[node][c] = v;
        }
        __syncthreads();
        int hb = half * 64;
#pragma unroll 1
        for (int k0 = 0; k0 < 64; k0 += 4) {
            float a[4][4];
#pragma unroll
            for (int i = 0; i < 4; ++i)
                *(float4*)&a[i][0] = *(const float4*)&As[ty + 16 * i][k0];
#pragma unroll
            for (int kk = 0; kk < 4; ++kk) {
                float4 b = *(const float4*)&Bs[hb + k0 + kk][tx4];
#pragma unroll
                for (int i = 0; i < 4; ++i) {
                    acc[i][0] += a[i][kk] * b.x;
                    acc[i][1] += a[i][kk] * b.y;
                    acc[i][2] += a[i][kk] * b.z;
                    acc[i][3] += a[i][kk] * b.w;
                }
            }
        }
    }

    // ---- msg epilogue: (acc + cnt*bmsg)/max(cnt,1) ----
    float bm[4];
#pragma unroll
    for (int j = 0; j < 4; ++j) bm[j] = bmsg[tx4 + j];
    float msg[4][4];
#pragma unroll
    for (int i = 0; i < 4; ++i) {
        int gn = block0 + ty + 16 * i;
        float c = (gn < NN) ? (float)counts[gn] : 0.f;
        float inv = 1.0f / fmaxf(c, 1.0f);
#pragma unroll
        for (int j = 0; j < 4; ++j) msg[i][j] = (acc[i][j] + c * bm[j]) * inv;
    }

    // ---- phase 2: apply GEMM ----
    __syncthreads();    // all reads of As(Esum)/Bs(Wmsg) complete
#pragma unroll 1
    for (int i = 0; i < 32; ++i) {
        int idx = i * 256 + tid;
        Bs[idx & 127][idx >> 7] = Wap[idx];
    }
#pragma unroll
    for (int i = 0; i < 4; ++i)
        *(float4*)&As[ty + 16 * i][tx4] = make_float4(msg[i][0], msg[i][1], msg[i][2], msg[i][3]);
    __syncthreads();

    float acc2[4][4] = {};
    // msg half (k in [64,128))
#pragma unroll 1
    for (int k0 = 0; k0 < 64; k0 += 4) {
        float a[4][4];
#pragma unroll
        for (int i = 0; i < 4; ++i)
            *(float4*)&a[i][0] = *(const float4*)&As[ty + 16 * i][k0];
#pragma unroll
        for (int kk = 0; kk < 4; ++kk) {
            float4 b = *(const float4*)&Bs[64 + k0 + kk][tx4];
#pragma unroll
            for (int i = 0; i < 4; ++i) {
                acc2[i][0] += a[i][kk] * b.x;
                acc2[i][1] += a[i][kk] * b.y;
                acc2[i][2] += a[i][kk] * b.z;
                acc2[i][3] += a[i][kk] * b.w;
            }
        }
    }
    __syncthreads();
    // Hprev half (k in [0,64))
#pragma unroll
    for (int g = 0; g < 4; ++g) {
        int idx = g * 256 + tid;
        int node = idx >> 4, c = (idx & 15) << 2;
        int gn = block0 + node;
        float4 v = make_float4(0.f, 0.f, 0.f, 0.f);
        if (gn < NN) v = *(const float4*)(Hprev + (size_t)gn * D + c);
        *(float4*)&As[node][c] = v;
    }
    __syncthreads();
#pragma unroll 1
    for (int k0 = 0; k0 < 64; k0 += 4) {
        float a[4][4];
#pragma unroll
        for (int i = 0; i < 4; ++i)
            *(float4*)&a[i][0] = *(const float4*)&As[ty + 16 * i][k0];
#pragma unroll
        for (int kk = 0; kk < 4; ++kk) {
            float4 b = *(const float4*)&Bs[k0 + kk][tx4];
#pragma unroll
            for (int i = 0; i < 4; ++i) {
                acc2[i][0] += a[i][kk] * b.x;
                acc2[i][1] += a[i][kk] * b.y;
                acc2[i][2] += a[i][kk] * b.z;
                acc2[i][3] += a[i][kk] * b.w;
            }
        }
    }

    // ---- epilogue ----
    float ba[4];
#pragma unroll
    for (int j = 0; j < 4; ++j) ba[j] = bap[tx4 + j];
    if (!do_loss) {
#pragma unroll
        for (int i = 0; i < 4; ++i) {
            int gn = block0 + ty + 16 * i;
            if (gn >= NN) continue;
#pragma unroll
            for (int j = 0; j < 4; ++j)
                Hout[(size_t)gn * D + tx4 + j] = fmaxf(acc2[i][j] + ba[j], 0.f);
        }
    } else {
        float lsum = 0.f;
#pragma unroll
        for (int i = 0; i < 4; ++i) {
            int gn = block0 + ty + 16 * i;
            if (gn >= NN) continue;
#pragma unroll
            for (int j = 0; j < 4; ++j) {
                float x = fmaxf(acc2[i][j] + ba[j], 0.f);
                float l = log1pf(expf(-x));   // pos: softplus(-x); neg adds x
                if (is_neg) l += x;
                lsum += l;
            }
        }
#pragma unroll
        for (int off = 32; off; off >>= 1) lsum += __shfl_down(lsum, off, 64);
        if ((tid & 63) == 0)
            unsafeAtomicAdd(loss_out, lsum * (1.0f / 6400000.0f)); // / (N*64)
    }
}

// ================= launch =================
extern "C" void kernel_launch(void* const* d_in, const int* in_sizes, int n_in,
                              void* d_out, int out_size, void* d_ws, size_t ws_size,
                              hipStream_t stream) {
    (void)in_sizes; (void)n_in; (void)out_size; (void)ws_size;
    const float* nfeats = (const float*)d_in[0];
    const float* efeats = (const float*)d_in[1];
    const int*   src    = (const int*)d_in[2];
    const int*   dst    = (const int*)d_in[3];
    const int*   perm   = (const int*)d_in[4];
    const float* Wmsg0  = (const float*)d_in[5];
    const float* bmsg0  = (const float*)d_in[6];
    const float* Wap0   = (const float*)d_in[7];
    const float* bap0   = (const float*)d_in[8];
    const float* Wmsg1  = (const float*)d_in[9];
    const float* bmsg1  = (const float*)d_in[10];
    const float* Wap1   = (const float*)d_in[11];
    const float* bap1   = (const float*)d_in[12];
    float* out = (float*)d_out;

    // ---- workspace layout (16B-aligned chunks) ----
    const size_t NV = (size_t)NN * D;
    char* p = (char*)d_ws;
    int4* sorted   = (int4*)p;               p += (size_t)NE * 16;   // 16 MB
    int*  rank     = (int*)p;                p += (size_t)NE * 4;    // 4 MB
    int*  counts   = (int*)p;                p += ((NN + 15) & ~15) * 4;
    int*  rowst    = (int*)p;                p += ((NN + 16) & ~15) * 4;
    int*  bsum     = (int*)p;                p += 512 * 4;
    int*  boff     = (int*)p;                p += 512 * 4;
    float* efs     = (float*)p;              p += NV * 4;            // 25.6 MB
    float* hsum0   = (float*)p;              p += NV * 4;
    float* h1      = (float*)p;              p += NV * 4;
    float* hsum1   = (float*)p;              p += NV * 4;

    const int EGb = (NE + 255) / 256;        // 3907
    const int PGb = ((size_t)NN * 64 + 255) / 256;  // 25000
    const int NG  = (NN + 63) / 64;          // 1563

    hipMemsetAsync(counts, 0, (size_t)NN * 4, stream);
    hipMemsetAsync(d_out, 0, 4, stream);

    // ---- CSR build ----
    k_hist<<<EGb, 256, 0, stream>>>(dst, counts, rank);
    k_scan1<<<NB_SCAN, 256, 0, stream>>>(counts, rowst, bsum);
    k_scan2<<<1, 512, 0, stream>>>(bsum, boff, rowst);
    k_scan3<<<NB_SCAN, 256, 0, stream>>>(rowst, boff);
    k_scatter<<<EGb, 256, 0, stream>>>(dst, src, perm, rank, rowst, sorted);

    // ---- positive encode ----
    pull_pass1<<<PGb, 256, 0, stream>>>(sorted, rowst, nfeats, efeats, hsum0, efs);
    fused_layer<<<NG, 256, 0, stream>>>(hsum0, efs, nfeats, counts,
                                        Wmsg0, bmsg0, Wap0, bap0, h1, 0, 0, nullptr);
    pull_h<<<PGb, 256, 0, stream>>>(sorted, rowst, h1, hsum1);
    fused_layer<<<NG, 256, 0, stream>>>(hsum1, efs, h1, counts,
                                        Wmsg1, bmsg1, Wap1, bap1, nullptr, 1, 0, out);

    // ---- negative encode (efsum from permuted edge features) ----
    pull_ef<<<PGb, 256, 0, stream>>>(sorted, rowst, efeats, efs);
    fused_layer<<<NG, 256, 0, stream>>>(hsum0, efs, nfeats, counts,
                                        Wmsg0, bmsg0, Wap0, bap0, h1, 0, 0, nullptr);
    pull_h<<<PGb, 256, 0, stream>>>(sorted, rowst, h1, hsum1);
    fused_layer<<<NG, 256, 0, stream>>>(hsum1, efs, h1, counts,
                                        Wmsg1, bmsg1, Wap1, bap1, nullptr, 1, 1, out);
}

// Round 4
// 1121.891 us; speedup vs baseline: 9.0467x; 1.1905x over previous
//
#include <hip/hip_runtime.h>
#include <math.h>

#define NN 100000
#define NE 1000000
#define D  64
#define NB_SCAN 391   // ceil(NN/256)

// ================= CSR build (counting sort by dst) =================

__global__ __launch_bounds__(256) void k_hist(
    const int* __restrict__ dst, int* __restrict__ counts, int* __restrict__ rank)
{
    int e = blockIdx.x * 256 + threadIdx.x;
    if (e >= NE) return;
    rank[e] = atomicAdd(&counts[dst[e]], 1);
}

__global__ __launch_bounds__(256) void k_scan1(
    const int* __restrict__ counts, int* __restrict__ row_start, int* __restrict__ bsum)
{
    __shared__ int s[256];
    int t = threadIdx.x;
    int i = blockIdx.x * 256 + t;
    int v = (i < NN) ? counts[i] : 0;
    s[t] = v; __syncthreads();
#pragma unroll
    for (int off = 1; off < 256; off <<= 1) {
        int add = (t >= off) ? s[t - off] : 0;
        __syncthreads();
        s[t] += add;
        __syncthreads();
    }
    if (i < NN) row_start[i] = s[t] - v;       // local exclusive
    if (t == 255) bsum[blockIdx.x] = s[255];   // block total
}

__global__ __launch_bounds__(512) void k_scan2(
    const int* __restrict__ bsum, int* __restrict__ boff, int* __restrict__ row_start)
{
    __shared__ int s[512];
    int t = threadIdx.x;
    int v = (t < NB_SCAN) ? bsum[t] : 0;
    s[t] = v; __syncthreads();
#pragma unroll
    for (int off = 1; off < 512; off <<= 1) {
        int add = (t >= off) ? s[t - off] : 0;
        __syncthreads();
        s[t] += add;
        __syncthreads();
    }
    if (t < NB_SCAN) boff[t] = s[t] - v;       // exclusive block offsets
    if (t == 0) row_start[NN] = NE;
}

__global__ __launch_bounds__(256) void k_scan3(
    int* __restrict__ row_start, const int* __restrict__ boff)
{
    int i = blockIdx.x * 256 + threadIdx.x;
    if (i < NN) row_start[i] += boff[i >> 8];
}

__global__ __launch_bounds__(256) void k_scatter(
    const int* __restrict__ dst, const int* __restrict__ src,
    const int* __restrict__ perm, const int* __restrict__ rank,
    const int* __restrict__ row_start, int4* __restrict__ sorted)
{
    int e = blockIdx.x * 256 + threadIdx.x;
    if (e >= NE) return;
    int pos = row_start[dst[e]] + rank[e];
    sorted[pos] = make_int4(src[e], e, perm[e], 0);
}

// ================= pull-based segment sums (no atomics) =================
// one wave per node; lane = channel. Manual unroll: batch index loads, then
// issue all row-gathers before accumulating (R3 was latency-bound at 1.5 TB/s:
// serial dependent loads -> ~2 rows in flight/wave; unroll-4/8 -> 8 rows).

__global__ __launch_bounds__(256) void pull_pass1(
    const int4* __restrict__ sorted, const int* __restrict__ row_start,
    const float* __restrict__ nfeats, const float* __restrict__ efeats,
    float* __restrict__ hsum0, float* __restrict__ efs)
{
    int gt = blockIdx.x * 256 + threadIdx.x;
    int w = gt >> 6, lane = gt & 63;
    if (w >= NN) return;
    int beg = row_start[w], end = row_start[w + 1];
    float ah = 0.f, ae = 0.f;
    int i = beg;
#pragma unroll 1
    for (; i + 4 <= end; i += 4) {
        int4 q0 = sorted[i], q1 = sorted[i + 1], q2 = sorted[i + 2], q3 = sorted[i + 3];
        float e0 = efeats[(size_t)q0.y * D + lane];
        float e1 = efeats[(size_t)q1.y * D + lane];
        float e2 = efeats[(size_t)q2.y * D + lane];
        float e3 = efeats[(size_t)q3.y * D + lane];
        float n0 = nfeats[(size_t)q0.x * D + lane];
        float n1 = nfeats[(size_t)q1.x * D + lane];
        float n2 = nfeats[(size_t)q2.x * D + lane];
        float n3 = nfeats[(size_t)q3.x * D + lane];
        ae += (e0 + e1) + (e2 + e3);
        ah += (n0 + n1) + (n2 + n3);
    }
#pragma unroll 1
    for (; i < end; ++i) {
        int4 q = sorted[i];
        ae += efeats[(size_t)q.y * D + lane];
        ah += nfeats[(size_t)q.x * D + lane];
    }
    hsum0[(size_t)w * D + lane] = ah;
    efs[(size_t)w * D + lane] = ae;
}

__global__ __launch_bounds__(256) void pull_h(
    const int4* __restrict__ sorted, const int* __restrict__ row_start,
    const float* __restrict__ h, float* __restrict__ hsum)
{
    int gt = blockIdx.x * 256 + threadIdx.x;
    int w = gt >> 6, lane = gt & 63;
    if (w >= NN) return;
    int beg = row_start[w], end = row_start[w + 1];
    float a = 0.f;
    int i = beg;
#pragma unroll 1
    for (; i + 8 <= end; i += 8) {
        int4 q0 = sorted[i],     q1 = sorted[i + 1], q2 = sorted[i + 2], q3 = sorted[i + 3];
        int4 q4 = sorted[i + 4], q5 = sorted[i + 5], q6 = sorted[i + 6], q7 = sorted[i + 7];
        float v0 = h[(size_t)q0.x * D + lane];
        float v1 = h[(size_t)q1.x * D + lane];
        float v2 = h[(size_t)q2.x * D + lane];
        float v3 = h[(size_t)q3.x * D + lane];
        float v4 = h[(size_t)q4.x * D + lane];
        float v5 = h[(size_t)q5.x * D + lane];
        float v6 = h[(size_t)q6.x * D + lane];
        float v7 = h[(size_t)q7.x * D + lane];
        a += ((v0 + v1) + (v2 + v3)) + ((v4 + v5) + (v6 + v7));
    }
#pragma unroll 1
    for (; i < end; ++i) {
        int4 q = sorted[i];
        a += h[(size_t)q.x * D + lane];
    }
    hsum[(size_t)w * D + lane] = a;
}

__global__ __launch_bounds__(256) void pull_ef(
    const int4* __restrict__ sorted, const int* __restrict__ row_start,
    const float* __restrict__ efeats, float* __restrict__ efs)
{
    int gt = blockIdx.x * 256 + threadIdx.x;
    int w = gt >> 6, lane = gt & 63;
    if (w >= NN) return;
    int beg = row_start[w], end = row_start[w + 1];
    float a = 0.f;
    int i = beg;
#pragma unroll 1
    for (; i + 8 <= end; i += 8) {
        int4 q0 = sorted[i],     q1 = sorted[i + 1], q2 = sorted[i + 2], q3 = sorted[i + 3];
        int4 q4 = sorted[i + 4], q5 = sorted[i + 5], q6 = sorted[i + 6], q7 = sorted[i + 7];
        float v0 = efeats[(size_t)q0.z * D + lane];
        float v1 = efeats[(size_t)q1.z * D + lane];
        float v2 = efeats[(size_t)q2.z * D + lane];
        float v3 = efeats[(size_t)q3.z * D + lane];
        float v4 = efeats[(size_t)q4.z * D + lane];
        float v5 = efeats[(size_t)q5.z * D + lane];
        float v6 = efeats[(size_t)q6.z * D + lane];
        float v7 = efeats[(size_t)q7.z * D + lane];
        a += ((v0 + v1) + (v2 + v3)) + ((v4 + v5) + (v6 + v7));
    }
#pragma unroll 1
    for (; i < end; ++i) {
        int4 q = sorted[i];
        a += efeats[(size_t)q.z * D + lane];
    }
    efs[(size_t)w * D + lane] = a;
}

// ================= fused SAGE layer: msg GEMM + apply GEMM =================
// 64 nodes x 64 outs per block, 256 threads, 4x4/thread (rows ty+16*i).
// __launch_bounds__(256,4) caps VGPR at 128; #pragma unroll 1 on k-loops
// prevents the full-unroll register balloon that caused scratch spills (R2:
// VGPR=256, 2.3 GB HBM traffic/dispatch from spill round-trips).
__global__ __launch_bounds__(256, 4) void fused_layer(
    const float* __restrict__ Hsum, const float* __restrict__ Esum,
    const float* __restrict__ Hprev, const int* __restrict__ counts,
    const float* __restrict__ Wmsg, const float* __restrict__ bmsg,
    const float* __restrict__ Wap, const float* __restrict__ bap,
    float* __restrict__ Hout, int do_loss, int is_neg, float* __restrict__ loss_out)
{
    __shared__ __align__(16) float As[64][68];
    __shared__ __align__(16) float Bs[128][68];
    int tid = threadIdx.x;
    int block0 = blockIdx.x * 64;
    int tx = tid & 15, ty = tid >> 4;
    int tx4 = tx << 2;

    // ---- stage Wmsg^T: Bs[k][o] = Wmsg[o*128+k] (coalesced global reads) ----
#pragma unroll 1
    for (int i = 0; i < 32; ++i) {
        int idx = i * 256 + tid;
        Bs[idx & 127][idx >> 7] = Wmsg[idx];
    }

    float acc[4][4] = {};
#pragma unroll
    for (int half = 0; half < 2; ++half) {
        const float* Asrc = half ? Esum : Hsum;
        __syncthreads();            // guards Bs on first pass, As reuse after
#pragma unroll
        for (int g = 0; g < 4; ++g) {
            int idx = g * 256 + tid;
            int node = idx >> 4, c = (idx & 15) << 2;
            int gn = block0 + node;
            float4 v = make_float4(0.f, 0.f, 0.f, 0.f);
            if (gn < NN) v = *(const float4*)(Asrc + (size_t)gn * D + c);
            *(float4*)&As[node][c] = v;
        }
        __syncthreads();
        int hb = half * 64;
#pragma unroll 1
        for (int k0 = 0; k0 < 64; k0 += 4) {
            float a[4][4];
#pragma unroll
            for (int i = 0; i < 4; ++i)
                *(float4*)&a[i][0] = *(const float4*)&As[ty + 16 * i][k0];
#pragma unroll
            for (int kk = 0; kk < 4; ++kk) {
                float4 b = *(const float4*)&Bs[hb + k0 + kk][tx4];
#pragma unroll
                for (int i = 0; i < 4; ++i) {
                    acc[i][0] += a[i][kk] * b.x;
                    acc[i][1] += a[i][kk] * b.y;
                    acc[i][2] += a[i][kk] * b.z;
                    acc[i][3] += a[i][kk] * b.w;
                }
            }
        }
    }

    // ---- msg epilogue: (acc + cnt*bmsg)/max(cnt,1) ----
    float bm[4];
#pragma unroll
    for (int j = 0; j < 4; ++j) bm[j] = bmsg[tx4 + j];
    float msg[4][4];
#pragma unroll
    for (int i = 0; i < 4; ++i) {
        int gn = block0 + ty + 16 * i;
        float c = (gn < NN) ? (float)counts[gn] : 0.f;
        float inv = 1.0f / fmaxf(c, 1.0f);
#pragma unroll
        for (int j = 0; j < 4; ++j) msg[i][j] = (acc[i][j] + c * bm[j]) * inv;
    }

    // ---- phase 2: apply GEMM ----
    __syncthreads();    // all reads of As(Esum)/Bs(Wmsg) complete
#pragma unroll 1
    for (int i = 0; i < 32; ++i) {
        int idx = i * 256 + tid;
        Bs[idx & 127][idx >> 7] = Wap[idx];
    }
#pragma unroll
    for (int i = 0; i < 4; ++i)
        *(float4*)&As[ty + 16 * i][tx4] = make_float4(msg[i][0], msg[i][1], msg[i][2], msg[i][3]);
    __syncthreads();

    float acc2[4][4] = {};
    // msg half (k in [64,128))
#pragma unroll 1
    for (int k0 = 0; k0 < 64; k0 += 4) {
        float a[4][4];
#pragma unroll
        for (int i = 0; i < 4; ++i)
            *(float4*)&a[i][0] = *(const float4*)&As[ty + 16 * i][k0];
#pragma unroll
        for (int kk = 0; kk < 4; ++kk) {
            float4 b = *(const float4*)&Bs[64 + k0 + kk][tx4];
#pragma unroll
            for (int i = 0; i < 4; ++i) {
                acc2[i][0] += a[i][kk] * b.x;
                acc2[i][1] += a[i][kk] * b.y;
                acc2[i][2] += a[i][kk] * b.z;
                acc2[i][3] += a[i][kk] * b.w;
            }
        }
    }
    __syncthreads();
    // Hprev half (k in [0,64))
#pragma unroll
    for (int g = 0; g < 4; ++g) {
        int idx = g * 256 + tid;
        int node = idx >> 4, c = (idx & 15) << 2;
        int gn = block0 + node;
        float4 v = make_float4(0.f, 0.f, 0.f, 0.f);
        if (gn < NN) v = *(const float4*)(Hprev + (size_t)gn * D + c);
        *(float4*)&As[node][c] = v;
    }
    __syncthreads();
#pragma unroll 1
    for (int k0 = 0; k0 < 64; k0 += 4) {
        float a[4][4];
#pragma unroll
        for (int i = 0; i < 4; ++i)
            *(float4*)&a[i][0] = *(const float4*)&As[ty + 16 * i][k0];
#pragma unroll
        for (int kk = 0; kk < 4; ++kk) {
            float4 b = *(const float4*)&Bs[k0 + kk][tx4];
#pragma unroll
            for (int i = 0; i < 4; ++i) {
                acc2[i][0] += a[i][kk] * b.x;
                acc2[i][1] += a[i][kk] * b.y;
                acc2[i][2] += a[i][kk] * b.z;
                acc2[i][3] += a[i][kk] * b.w;
            }
        }
    }

    // ---- epilogue ----
    float ba[4];
#pragma unroll
    for (int j = 0; j < 4; ++j) ba[j] = bap[tx4 + j];
    if (!do_loss) {
#pragma unroll
        for (int i = 0; i < 4; ++i) {
            int gn = block0 + ty + 16 * i;
            if (gn >= NN) continue;
#pragma unroll
            for (int j = 0; j < 4; ++j)
                Hout[(size_t)gn * D + tx4 + j] = fmaxf(acc2[i][j] + ba[j], 0.f);
        }
    } else {
        float lsum = 0.f;
#pragma unroll
        for (int i = 0; i < 4; ++i) {
            int gn = block0 + ty + 16 * i;
            if (gn >= NN) continue;
#pragma unroll
            for (int j = 0; j < 4; ++j) {
                float x = fmaxf(acc2[i][j] + ba[j], 0.f);
                float l = log1pf(expf(-x));   // pos: softplus(-x); neg adds x
                if (is_neg) l += x;
                lsum += l;
            }
        }
#pragma unroll
        for (int off = 32; off; off >>= 1) lsum += __shfl_down(lsum, off, 64);
        if ((tid & 63) == 0)
            unsafeAtomicAdd(loss_out, lsum * (1.0f / 6400000.0f)); // / (N*64)
    }
}

// ================= launch =================
extern "C" void kernel_launch(void* const* d_in, const int* in_sizes, int n_in,
                              void* d_out, int out_size, void* d_ws, size_t ws_size,
                              hipStream_t stream) {
    (void)in_sizes; (void)n_in; (void)out_size; (void)ws_size;
    const float* nfeats = (const float*)d_in[0];
    const float* efeats = (const float*)d_in[1];
    const int*   src    = (const int*)d_in[2];
    const int*   dst    = (const int*)d_in[3];
    const int*   perm   = (const int*)d_in[4];
    const float* Wmsg0  = (const float*)d_in[5];
    const float* bmsg0  = (const float*)d_in[6];
    const float* Wap0   = (const float*)d_in[7];
    const float* bap0   = (const float*)d_in[8];
    const float* Wmsg1  = (const float*)d_in[9];
    const float* bmsg1  = (const float*)d_in[10];
    const float* Wap1   = (const float*)d_in[11];
    const float* bap1   = (const float*)d_in[12];
    float* out = (float*)d_out;

    // ---- workspace layout (16B-aligned chunks) ----
    const size_t NV = (size_t)NN * D;
    char* p = (char*)d_ws;
    int4* sorted   = (int4*)p;               p += (size_t)NE * 16;   // 16 MB
    int*  rank     = (int*)p;                p += (size_t)NE * 4;    // 4 MB
    int*  counts   = (int*)p;                p += ((NN + 15) & ~15) * 4;
    int*  rowst    = (int*)p;                p += ((NN + 16) & ~15) * 4;
    int*  bsum     = (int*)p;                p += 512 * 4;
    int*  boff     = (int*)p;                p += 512 * 4;
    float* efs     = (float*)p;              p += NV * 4;            // 25.6 MB
    float* hsum0   = (float*)p;              p += NV * 4;
    float* h1      = (float*)p;              p += NV * 4;
    float* hsum1   = (float*)p;              p += NV * 4;

    const int EGb = (NE + 255) / 256;        // 3907
    const int PGb = ((size_t)NN * 64 + 255) / 256;  // 25000
    const int NG  = (NN + 63) / 64;          // 1563

    hipMemsetAsync(counts, 0, (size_t)NN * 4, stream);
    hipMemsetAsync(d_out, 0, 4, stream);

    // ---- CSR build ----
    k_hist<<<EGb, 256, 0, stream>>>(dst, counts, rank);
    k_scan1<<<NB_SCAN, 256, 0, stream>>>(counts, rowst, bsum);
    k_scan2<<<1, 512, 0, stream>>>(bsum, boff, rowst);
    k_scan3<<<NB_SCAN, 256, 0, stream>>>(rowst, boff);
    k_scatter<<<EGb, 256, 0, stream>>>(dst, src, perm, rank, rowst, sorted);

    // ---- positive encode ----
    pull_pass1<<<PGb, 256, 0, stream>>>(sorted, rowst, nfeats, efeats, hsum0, efs);
    fused_layer<<<NG, 256, 0, stream>>>(hsum0, efs, nfeats, counts,
                                        Wmsg0, bmsg0, Wap0, bap0, h1, 0, 0, nullptr);
    pull_h<<<PGb, 256, 0, stream>>>(sorted, rowst, h1, hsum1);
    fused_layer<<<NG, 256, 0, stream>>>(hsum1, efs, h1, counts,
                                        Wmsg1, bmsg1, Wap1, bap1, nullptr, 1, 0, out);

    // ---- negative encode (efsum from permuted edge features) ----
    pull_ef<<<PGb, 256, 0, stream>>>(sorted, rowst, efeats, efs);
    fused_layer<<<NG, 256, 0, stream>>>(hsum0, efs, nfeats, counts,
                                        Wmsg0, bmsg0, Wap0, bap0, h1, 0, 0, nullptr);
    pull_h<<<PGb, 256, 0, stream>>>(sorted, rowst, h1, hsum1);
    fused_layer<<<NG, 256, 0, stream>>>(hsum1, efs, h1, counts,
                                        Wmsg1, bmsg1, Wap1, bap1, nullptr, 1, 1, out);
}

// Round 5
// 1028.756 us; speedup vs baseline: 9.8657x; 1.0905x over previous
//
#include <hip/hip_runtime.h>
#include <math.h>

#define NN 100000
#define NE 1000000
#define D  64
#define NB_SCAN 391   // ceil(NN/256)

// ================= CSR build (counting sort by dst) =================

__global__ __launch_bounds__(256) void k_hist(
    const int* __restrict__ dst, int* __restrict__ counts, int* __restrict__ rank)
{
    int e = blockIdx.x * 256 + threadIdx.x;
    if (e >= NE) return;
    rank[e] = atomicAdd(&counts[dst[e]], 1);
}

__global__ __launch_bounds__(256) void k_scan1(
    const int* __restrict__ counts, int* __restrict__ row_start, int* __restrict__ bsum)
{
    __shared__ int s[256];
    int t = threadIdx.x;
    int i = blockIdx.x * 256 + t;
    int v = (i < NN) ? counts[i] : 0;
    s[t] = v; __syncthreads();
#pragma unroll
    for (int off = 1; off < 256; off <<= 1) {
        int add = (t >= off) ? s[t - off] : 0;
        __syncthreads();
        s[t] += add;
        __syncthreads();
    }
    if (i < NN) row_start[i] = s[t] - v;       // local exclusive
    if (t == 255) bsum[blockIdx.x] = s[255];   // block total
}

__global__ __launch_bounds__(512) void k_scan2(
    const int* __restrict__ bsum, int* __restrict__ boff, int* __restrict__ row_start)
{
    __shared__ int s[512];
    int t = threadIdx.x;
    int v = (t < NB_SCAN) ? bsum[t] : 0;
    s[t] = v; __syncthreads();
#pragma unroll
    for (int off = 1; off < 512; off <<= 1) {
        int add = (t >= off) ? s[t - off] : 0;
        __syncthreads();
        s[t] += add;
        __syncthreads();
    }
    if (t < NB_SCAN) boff[t] = s[t] - v;       // exclusive block offsets
    if (t == 0) row_start[NN] = NE;
}

__global__ __launch_bounds__(256) void k_scan3(
    int* __restrict__ row_start, const int* __restrict__ boff)
{
    int i = blockIdx.x * 256 + threadIdx.x;
    if (i < NN) row_start[i] += boff[i >> 8];
}

__global__ __launch_bounds__(256) void k_scatter(
    const int* __restrict__ dst, const int* __restrict__ src,
    const int* __restrict__ perm, const int* __restrict__ rank,
    const int* __restrict__ row_start, int4* __restrict__ sorted)
{
    int e = blockIdx.x * 256 + threadIdx.x;
    if (e >= NE) return;
    int pos = row_start[dst[e]] + rank[e];
    sorted[pos] = make_int4(src[e], e, perm[e], 0);
}

// ================= pull-based segment sums (no atomics) =================
// wave = node; lane = (edge_slot es=lane>>4, chan4 c4=(lane&15)*4).
// Each lane gathers float4 (16B) — 4 edges per wave-iter, 4x fewer mem
// instructions than the R4 scalar version. Butterfly shfl_xor(16,32) folds
// the 4 edge slots; lanes 0..15 store the 64-ch row as float4.

__global__ __launch_bounds__(256) void pull_pass1(
    const int4* __restrict__ sorted, const int* __restrict__ row_start,
    const float* __restrict__ nfeats, const float* __restrict__ efeats,
    float* __restrict__ hsum0, float* __restrict__ efsP, float* __restrict__ efsN)
{
    int gt = blockIdx.x * 256 + threadIdx.x;
    int w = gt >> 6, lane = gt & 63;
    if (w >= NN) return;
    int es = lane >> 4, c4 = (lane & 15) << 2;
    int beg = row_start[w], end = row_start[w + 1];

    float an0 = 0.f, an1 = 0.f, an2 = 0.f, an3 = 0.f;
    float ap0 = 0.f, ap1 = 0.f, ap2 = 0.f, ap3 = 0.f;
    float ag0 = 0.f, ag1 = 0.f, ag2 = 0.f, ag3 = 0.f;
#pragma unroll 1
    for (int i = beg + es; i < end; i += 4) {
        int4 q = sorted[i];
        float4 n  = *(const float4*)(nfeats + (size_t)q.x * D + c4);
        float4 ep = *(const float4*)(efeats + (size_t)q.y * D + c4);
        float4 en = *(const float4*)(efeats + (size_t)q.z * D + c4);
        an0 += n.x;  an1 += n.y;  an2 += n.z;  an3 += n.w;
        ap0 += ep.x; ap1 += ep.y; ap2 += ep.z; ap3 += ep.w;
        ag0 += en.x; ag1 += en.y; ag2 += en.z; ag3 += en.w;
    }
#pragma unroll
    for (int off = 16; off <= 32; off <<= 1) {
        an0 += __shfl_xor(an0, off, 64); an1 += __shfl_xor(an1, off, 64);
        an2 += __shfl_xor(an2, off, 64); an3 += __shfl_xor(an3, off, 64);
        ap0 += __shfl_xor(ap0, off, 64); ap1 += __shfl_xor(ap1, off, 64);
        ap2 += __shfl_xor(ap2, off, 64); ap3 += __shfl_xor(ap3, off, 64);
        ag0 += __shfl_xor(ag0, off, 64); ag1 += __shfl_xor(ag1, off, 64);
        ag2 += __shfl_xor(ag2, off, 64); ag3 += __shfl_xor(ag3, off, 64);
    }
    if (lane < 16) {
        *(float4*)(hsum0 + (size_t)w * D + c4) = make_float4(an0, an1, an2, an3);
        *(float4*)(efsP  + (size_t)w * D + c4) = make_float4(ap0, ap1, ap2, ap3);
        *(float4*)(efsN  + (size_t)w * D + c4) = make_float4(ag0, ag1, ag2, ag3);
    }
}

__global__ __launch_bounds__(256) void pull_h(
    const int4* __restrict__ sorted, const int* __restrict__ row_start,
    const float* __restrict__ h, float* __restrict__ hsum)
{
    int gt = blockIdx.x * 256 + threadIdx.x;
    int w = gt >> 6, lane = gt & 63;
    if (w >= NN) return;
    int es = lane >> 4, c4 = (lane & 15) << 2;
    int beg = row_start[w], end = row_start[w + 1];

    float a0 = 0.f, a1 = 0.f, a2 = 0.f, a3 = 0.f;
#pragma unroll 2
    for (int i = beg + es; i < end; i += 4) {
        int4 q = sorted[i];
        float4 v = *(const float4*)(h + (size_t)q.x * D + c4);
        a0 += v.x; a1 += v.y; a2 += v.z; a3 += v.w;
    }
#pragma unroll
    for (int off = 16; off <= 32; off <<= 1) {
        a0 += __shfl_xor(a0, off, 64); a1 += __shfl_xor(a1, off, 64);
        a2 += __shfl_xor(a2, off, 64); a3 += __shfl_xor(a3, off, 64);
    }
    if (lane < 16)
        *(float4*)(hsum + (size_t)w * D + c4) = make_float4(a0, a1, a2, a3);
}

// ================= fused SAGE layer: msg GEMM + apply GEMM =================
// 64 nodes x 64 outs per block, 256 threads, 4x4/thread (rows ty+16*i).
// __launch_bounds__(256,4) caps VGPR at 128; #pragma unroll 1 on k-loops
// prevents the full-unroll register balloon that caused scratch spills (R2:
// VGPR=256, 2.3 GB HBM traffic/dispatch from spill round-trips).
__global__ __launch_bounds__(256, 4) void fused_layer(
    const float* __restrict__ Hsum, const float* __restrict__ Esum,
    const float* __restrict__ Hprev, const int* __restrict__ counts,
    const float* __restrict__ Wmsg, const float* __restrict__ bmsg,
    const float* __restrict__ Wap, const float* __restrict__ bap,
    float* __restrict__ Hout, int do_loss, int is_neg, float* __restrict__ loss_out)
{
    __shared__ __align__(16) float As[64][68];
    __shared__ __align__(16) float Bs[128][68];
    int tid = threadIdx.x;
    int block0 = blockIdx.x * 64;
    int tx = tid & 15, ty = tid >> 4;
    int tx4 = tx << 2;

    // ---- stage Wmsg^T: Bs[k][o] = Wmsg[o*128+k] (coalesced global reads) ----
#pragma unroll 1
    for (int i = 0; i < 32; ++i) {
        int idx = i * 256 + tid;
        Bs[idx & 127][idx >> 7] = Wmsg[idx];
    }

    float acc[4][4] = {};
#pragma unroll
    for (int half = 0; half < 2; ++half) {
        const float* Asrc = half ? Esum : Hsum;
        __syncthreads();            // guards Bs on first pass, As reuse after
#pragma unroll
        for (int g = 0; g < 4; ++g) {
            int idx = g * 256 + tid;
            int node = idx >> 4, c = (idx & 15) << 2;
            int gn = block0 + node;
            float4 v = make_float4(0.f, 0.f, 0.f, 0.f);
            if (gn < NN) v = *(const float4*)(Asrc + (size_t)gn * D + c);
            *(float4*)&As[node][c] = v;
        }
        __syncthreads();
        int hb = half * 64;
#pragma unroll 1
        for (int k0 = 0; k0 < 64; k0 += 4) {
            float a[4][4];
#pragma unroll
            for (int i = 0; i < 4; ++i)
                *(float4*)&a[i][0] = *(const float4*)&As[ty + 16 * i][k0];
#pragma unroll
            for (int kk = 0; kk < 4; ++kk) {
                float4 b = *(const float4*)&Bs[hb + k0 + kk][tx4];
#pragma unroll
                for (int i = 0; i < 4; ++i) {
                    acc[i][0] += a[i][kk] * b.x;
                    acc[i][1] += a[i][kk] * b.y;
                    acc[i][2] += a[i][kk] * b.z;
                    acc[i][3] += a[i][kk] * b.w;
                }
            }
        }
    }

    // ---- msg epilogue: (acc + cnt*bmsg)/max(cnt,1) ----
    float bm[4];
#pragma unroll
    for (int j = 0; j < 4; ++j) bm[j] = bmsg[tx4 + j];
    float msg[4][4];
#pragma unroll
    for (int i = 0; i < 4; ++i) {
        int gn = block0 + ty + 16 * i;
        float c = (gn < NN) ? (float)counts[gn] : 0.f;
        float inv = 1.0f / fmaxf(c, 1.0f);
#pragma unroll
        for (int j = 0; j < 4; ++j) msg[i][j] = (acc[i][j] + c * bm[j]) * inv;
    }

    // ---- phase 2: apply GEMM ----
    __syncthreads();    // all reads of As(Esum)/Bs(Wmsg) complete
#pragma unroll 1
    for (int i = 0; i < 32; ++i) {
        int idx = i * 256 + tid;
        Bs[idx & 127][idx >> 7] = Wap[idx];
    }
#pragma unroll
    for (int i = 0; i < 4; ++i)
        *(float4*)&As[ty + 16 * i][tx4] = make_float4(msg[i][0], msg[i][1], msg[i][2], msg[i][3]);
    __syncthreads();

    float acc2[4][4] = {};
    // msg half (k in [64,128))
#pragma unroll 1
    for (int k0 = 0; k0 < 64; k0 += 4) {
        float a[4][4];
#pragma unroll
        for (int i = 0; i < 4; ++i)
            *(float4*)&a[i][0] = *(const float4*)&As[ty + 16 * i][k0];
#pragma unroll
        for (int kk = 0; kk < 4; ++kk) {
            float4 b = *(const float4*)&Bs[64 + k0 + kk][tx4];
#pragma unroll
            for (int i = 0; i < 4; ++i) {
                acc2[i][0] += a[i][kk] * b.x;
                acc2[i][1] += a[i][kk] * b.y;
                acc2[i][2] += a[i][kk] * b.z;
                acc2[i][3] += a[i][kk] * b.w;
            }
        }
    }
    __syncthreads();
    // Hprev half (k in [0,64))
#pragma unroll
    for (int g = 0; g < 4; ++g) {
        int idx = g * 256 + tid;
        int node = idx >> 4, c = (idx & 15) << 2;
        int gn = block0 + node;
        float4 v = make_float4(0.f, 0.f, 0.f, 0.f);
        if (gn < NN) v = *(const float4*)(Hprev + (size_t)gn * D + c);
        *(float4*)&As[node][c] = v;
    }
    __syncthreads();
#pragma unroll 1
    for (int k0 = 0; k0 < 64; k0 += 4) {
        float a[4][4];
#pragma unroll
        for (int i = 0; i < 4; ++i)
            *(float4*)&a[i][0] = *(const float4*)&As[ty + 16 * i][k0];
#pragma unroll
        for (int kk = 0; kk < 4; ++kk) {
            float4 b = *(const float4*)&Bs[k0 + kk][tx4];
#pragma unroll
            for (int i = 0; i < 4; ++i) {
                acc2[i][0] += a[i][kk] * b.x;
                acc2[i][1] += a[i][kk] * b.y;
                acc2[i][2] += a[i][kk] * b.z;
                acc2[i][3] += a[i][kk] * b.w;
            }
        }
    }

    // ---- epilogue ----
    float ba[4];
#pragma unroll
    for (int j = 0; j < 4; ++j) ba[j] = bap[tx4 + j];
    if (!do_loss) {
#pragma unroll
        for (int i = 0; i < 4; ++i) {
            int gn = block0 + ty + 16 * i;
            if (gn >= NN) continue;
#pragma unroll
            for (int j = 0; j < 4; ++j)
                Hout[(size_t)gn * D + tx4 + j] = fmaxf(acc2[i][j] + ba[j], 0.f);
        }
    } else {
        float lsum = 0.f;
#pragma unroll
        for (int i = 0; i < 4; ++i) {
            int gn = block0 + ty + 16 * i;
            if (gn >= NN) continue;
#pragma unroll
            for (int j = 0; j < 4; ++j) {
                float x = fmaxf(acc2[i][j] + ba[j], 0.f);
                float l = log1pf(expf(-x));   // pos: softplus(-x); neg adds x
                if (is_neg) l += x;
                lsum += l;
            }
        }
#pragma unroll
        for (int off = 32; off; off >>= 1) lsum += __shfl_down(lsum, off, 64);
        if ((tid & 63) == 0)
            unsafeAtomicAdd(loss_out, lsum * (1.0f / 6400000.0f)); // / (N*64)
    }
}

// ================= launch =================
extern "C" void kernel_launch(void* const* d_in, const int* in_sizes, int n_in,
                              void* d_out, int out_size, void* d_ws, size_t ws_size,
                              hipStream_t stream) {
    (void)in_sizes; (void)n_in; (void)out_size; (void)ws_size;
    const float* nfeats = (const float*)d_in[0];
    const float* efeats = (const float*)d_in[1];
    const int*   src    = (const int*)d_in[2];
    const int*   dst    = (const int*)d_in[3];
    const int*   perm   = (const int*)d_in[4];
    const float* Wmsg0  = (const float*)d_in[5];
    const float* bmsg0  = (const float*)d_in[6];
    const float* Wap0   = (const float*)d_in[7];
    const float* bap0   = (const float*)d_in[8];
    const float* Wmsg1  = (const float*)d_in[9];
    const float* bmsg1  = (const float*)d_in[10];
    const float* Wap1   = (const float*)d_in[11];
    const float* bap1   = (const float*)d_in[12];
    float* out = (float*)d_out;

    // ---- workspace layout (16B-aligned chunks) ----
    const size_t NV = (size_t)NN * D;
    char* p = (char*)d_ws;
    int4* sorted   = (int4*)p;               p += (size_t)NE * 16;   // 16 MB
    int*  rank     = (int*)p;                p += (size_t)NE * 4;    // 4 MB
    int*  counts   = (int*)p;                p += ((NN + 15) & ~15) * 4;
    int*  rowst    = (int*)p;                p += ((NN + 16) & ~15) * 4;
    int*  bsum     = (int*)p;                p += 512 * 4;
    int*  boff     = (int*)p;                p += 512 * 4;
    float* efsP    = (float*)p;              p += NV * 4;            // 25.6 MB
    float* efsN    = (float*)p;              p += NV * 4;
    float* hsum0   = (float*)p;              p += NV * 4;
    float* h1      = (float*)p;              p += NV * 4;
    float* hsum1   = (float*)p;              p += NV * 4;

    const int EGb = (NE + 255) / 256;        // 3907
    const int PGb = ((size_t)NN * 64 + 255) / 256;  // 25000
    const int NG  = (NN + 63) / 64;          // 1563

    hipMemsetAsync(counts, 0, (size_t)NN * 4, stream);
    hipMemsetAsync(d_out, 0, 4, stream);

    // ---- CSR build ----
    k_hist<<<EGb, 256, 0, stream>>>(dst, counts, rank);
    k_scan1<<<NB_SCAN, 256, 0, stream>>>(counts, rowst, bsum);
    k_scan2<<<1, 512, 0, stream>>>(bsum, boff, rowst);
    k_scan3<<<NB_SCAN, 256, 0, stream>>>(rowst, boff);
    k_scatter<<<EGb, 256, 0, stream>>>(dst, src, perm, rank, rowst, sorted);

    // ---- all first-layer segment sums in one pass (pos ef, neg ef, nfeats) ----
    pull_pass1<<<PGb, 256, 0, stream>>>(sorted, rowst, nfeats, efeats, hsum0, efsP, efsN);

    // ---- positive encode ----
    fused_layer<<<NG, 256, 0, stream>>>(hsum0, efsP, nfeats, counts,
                                        Wmsg0, bmsg0, Wap0, bap0, h1, 0, 0, nullptr);
    pull_h<<<PGb, 256, 0, stream>>>(sorted, rowst, h1, hsum1);
    fused_layer<<<NG, 256, 0, stream>>>(hsum1, efsP, h1, counts,
                                        Wmsg1, bmsg1, Wap1, bap1, nullptr, 1, 0, out);

    // ---- negative encode ----
    fused_layer<<<NG, 256, 0, stream>>>(hsum0, efsN, nfeats, counts,
                                        Wmsg0, bmsg0, Wap0, bap0, h1, 0, 0, nullptr);
    pull_h<<<PGb, 256, 0, stream>>>(sorted, rowst, h1, hsum1);
    fused_layer<<<NG, 256, 0, stream>>>(hsum1, efsN, h1, counts,
                                        Wmsg1, bmsg1, Wap1, bap1, nullptr, 1, 1, out);
}